// Round 16
// baseline (1826.067 us; speedup 1.0000x reference)
//
#include <hip/hip_runtime.h>
#include <hip/hip_bf16.h>

// GrCNet attention layer — R15 3-kernel pipeline + amplified timing probes.
// R15's big structural cut (5->3 kernels) gained only 1.4us => per-kernel
// ledger is wrong again. Probes (scratch-writing, x20-30 reps) re-measure
// node_mfma / histplace / aggregate on the real data so the next round
// targets the actual whale. Real pipeline unchanged -> output identical.

#define LRELU_ALPHA 0.2f
#define PITCH 72
#define SLOTS 64

#define REPS_NODE 30
#define REPS_HP   20
#define REPS_AGG  20

typedef __attribute__((ext_vector_type(8))) short bf16x8;
typedef __attribute__((ext_vector_type(4))) float f32x4;

__device__ __forceinline__ float bflo(unsigned int q) {
    return __int_as_float((int)(q << 16));
}
__device__ __forceinline__ float bfhi(unsigned int q) {
    return __int_as_float((int)(q & 0xffff0000u));
}
__device__ __forceinline__ unsigned short f2bf(float f) {
    __hip_bfloat16 h = __float2bfloat16(f);
    return *reinterpret_cast<unsigned short*>(&h);
}

// ---------------- real kernels (identical to R15) ----------------

__global__ __launch_bounds__(256) void node_mfma_kernel(
    const float* __restrict__ x, const float* __restrict__ a,
    const float* __restrict__ a2,
    unsigned short* __restrict__ u_bf, unsigned short* __restrict__ v_bf,
    float* __restrict__ su, float* __restrict__ sv,
    int* __restrict__ count, int N)
{
    __shared__ unsigned short xl[64 * PITCH];
    __shared__ unsigned short bl[128 * PITCH];
    const int t = threadIdx.x;
    const int rowbase = blockIdx.x * 64;

    {
        const int row = t & 63, q = t >> 6;
        const int grow = rowbase + row;
        float xv[16];
        if (grow < N) {
            const float4* xp = (const float4*)(x + (size_t)grow * 64 + q * 16);
#pragma unroll
            for (int k = 0; k < 4; ++k) {
                const float4 f = xp[k];
                xv[k * 4 + 0] = f.x; xv[k * 4 + 1] = f.y;
                xv[k * 4 + 2] = f.z; xv[k * 4 + 3] = f.w;
            }
        } else {
#pragma unroll
            for (int k = 0; k < 16; ++k) xv[k] = 0.f;
        }
        unsigned int uu[8];
#pragma unroll
        for (int k = 0; k < 8; ++k)
            uu[k] = (unsigned int)f2bf(xv[2 * k]) |
                    ((unsigned int)f2bf(xv[2 * k + 1]) << 16);
        uint4* dst = (uint4*)&xl[row * PITCH + q * 16];
        dst[0] = make_uint4(uu[0], uu[1], uu[2], uu[3]);
        dst[1] = make_uint4(uu[4], uu[5], uu[6], uu[7]);
    }
    {
        const int op = t >> 1, hh = (t & 1) * 32;
        const float* src = (op < 64) ? (a + op * 128 + hh)
                                     : (a + (op - 64) * 128 + 64 + hh);
        unsigned int uu[16];
#pragma unroll
        for (int k = 0; k < 16; ++k)
            uu[k] = (unsigned int)f2bf(src[2 * k]) |
                    ((unsigned int)f2bf(src[2 * k + 1]) << 16);
        uint4* dst = (uint4*)&bl[op * PITCH + hh];
#pragma unroll
        for (int k = 0; k < 4; ++k)
            dst[k] = make_uint4(uu[4 * k], uu[4 * k + 1], uu[4 * k + 2], uu[4 * k + 3]);
    }
    if (t < 64 && rowbase + t < N) count[rowbase + t] = 0;
    __syncthreads();

    const int w = t >> 6, l = t & 63;
    const int rw = w * 16;
    const int lr = l & 15, lk = l >> 4;

    const bf16x8 af0 = *(const bf16x8*)&xl[(rw + lr) * PITCH + lk * 8];
    const bf16x8 af1 = *(const bf16x8*)&xl[(rw + lr) * PITCH + 32 + lk * 8];

    float sup[4] = {0.f, 0.f, 0.f, 0.f}, svp[4] = {0.f, 0.f, 0.f, 0.f};

    for (int ct = 0; ct < 8; ++ct) {
        const bf16x8 bf0 = *(const bf16x8*)&bl[(ct * 16 + lr) * PITCH + lk * 8];
        const bf16x8 bf1 = *(const bf16x8*)&bl[(ct * 16 + lr) * PITCH + 32 + lk * 8];
        f32x4 acc = {0.f, 0.f, 0.f, 0.f};
        acc = __builtin_amdgcn_mfma_f32_16x16x32_bf16(af0, bf0, acc, 0, 0, 0);
        acc = __builtin_amdgcn_mfma_f32_16x16x32_bf16(af1, bf1, acc, 0, 0, 0);

        const int col = ct * 16 + lr;
        unsigned short* dst = (ct < 4) ? u_bf : v_bf;
        const int o = (ct < 4) ? col : col - 64;
        const float a2o = a2[o];
#pragma unroll
        for (int r = 0; r < 4; ++r) {
            const int grow = rowbase + rw + lk * 4 + r;
            if (grow < N) dst[(size_t)grow * 64 + o] = f2bf(acc[r]);
            if (ct < 4) sup[r] += acc[r] * a2o; else svp[r] += acc[r] * a2o;
        }
    }

#pragma unroll
    for (int r = 0; r < 4; ++r) {
#pragma unroll
        for (int m = 1; m < 16; m <<= 1) {
            sup[r] += __shfl_xor(sup[r], m, 64);
            svp[r] += __shfl_xor(svp[r], m, 64);
        }
    }
    if (lr == 0) {
#pragma unroll
        for (int r = 0; r < 4; ++r) {
            const int grow = rowbase + rw + lk * 4 + r;
            if (grow < N) { su[grow] = sup[r]; sv[grow] = svp[r]; }
        }
    }
}

__global__ __launch_bounds__(256) void histplace_kernel(
    const int* __restrict__ edge, const int* __restrict__ etype,
    int* __restrict__ count, unsigned int* __restrict__ csr,
    int E, int N, int R)
{
    const int i4 = (blockIdx.x * 256 + threadIdx.x) * 4;
    if (i4 + 3 < E) {
        const int4 s4 = *(const int4*)(edge + i4);
        const int4 d4 = *(const int4*)(edge + (size_t)E + i4);
        const int4 t4 = *(const int4*)(etype + i4);
        const int ss[4] = {s4.x, s4.y, s4.z, s4.w};
        const int dd[4] = {d4.x, d4.y, d4.z, d4.w};
        const int tt[4] = {t4.x, t4.y, t4.z, t4.w};
#pragma unroll
        for (int k = 0; k < 4; ++k) {
            if ((unsigned)ss[k] < (unsigned)N && (unsigned)dd[k] < (unsigned)N &&
                (unsigned)tt[k] < (unsigned)R) {
                const int slot = atomicAdd(&count[ss[k]], 1);
                if (slot < SLOTS)
                    csr[(size_t)ss[k] * SLOTS + slot] =
                        ((unsigned)dd[k] << 8) | (unsigned)tt[k];
            }
        }
    } else {
        for (int i = i4; i < E; ++i) {
            const int s = edge[i];
            const int d = edge[(size_t)E + i];
            const int t = etype[i];
            if ((unsigned)s < (unsigned)N && (unsigned)d < (unsigned)N &&
                (unsigned)t < (unsigned)R) {
                const int slot = atomicAdd(&count[s], 1);
                if (slot < SLOTS)
                    csr[(size_t)s * SLOTS + slot] =
                        ((unsigned)d << 8) | (unsigned)t;
            }
        }
    }
}

__global__ __launch_bounds__(256) void aggregate_kernel(
    const int* __restrict__ count,
    const unsigned int* __restrict__ csr,
    const uint2* __restrict__ u_bf4,
    const uint2* __restrict__ v_bf4,
    const float* __restrict__ su, const float* __restrict__ sv,
    const float* __restrict__ G, int R,
    float* __restrict__ out, int N)
{
    const int wave = threadIdx.x >> 6;
    const int lane = threadIdx.x & 63;
    const int n = blockIdx.x * 4 + wave;
    if (n >= N) return;

    const int m = min(count[n], SLOTS);
    const unsigned int* __restrict__ row = csr + (size_t)n * SLOTS;

    const int c = lane & 15;
    const int r = lane >> 4;

    const float su_n = su[n];
    const float* __restrict__ Gn = G + (size_t)n * R;

    float v0 = 0.f, v1 = 0.f, v2 = 0.f, v3 = 0.f;

    unsigned pe = 0;
    if (lane < m) pe = row[lane];
    const int dl = (int)(pe >> 8);

    const int   dA0 = __shfl(dl, 0 + r, 64);
    const int   dB0 = __shfl(dl, 4 + r, 64);
    const uint2 qa0 = v_bf4[(size_t)dA0 * 16 + c];
    const uint2 qb0 = v_bf4[(size_t)dB0 * 16 + c];
    uint2 qa1 = make_uint2(0u, 0u), qb1 = make_uint2(0u, 0u);
    if (m > 8) {
        const int dA1 = __shfl(dl, 8 + r, 64);
        const int dB1 = __shfl(dl, 12 + r, 64);
        qa1 = v_bf4[(size_t)dA1 * 16 + c];
        qb1 = v_bf4[(size_t)dB1 * 16 + c];
    }

    float wl = 0.f, eel = 0.f;
    if (lane < m) {
        const int t = (int)(pe & 255u);
        const float g   = 0.5f * (Gn[t] + G[(size_t)dl * R + t]);
        const float raw = g * (su_n + sv[dl]);
        const float lr  = raw > 0.f ? raw : LRELU_ALPHA * raw;
        const float ee  = __expf(-lr);
        eel = ee;
        wl  = ee * g;
    }
    float sumw = wl, sumee = eel;

    {
        const float wA = __shfl(wl, 0 + r, 64);
        const float wB = __shfl(wl, 4 + r, 64);
        v0 += wA * bflo(qa0.x);  v1 += wA * bfhi(qa0.x);
        v2 += wA * bflo(qa0.y);  v3 += wA * bfhi(qa0.y);
        v0 += wB * bflo(qb0.x);  v1 += wB * bfhi(qb0.x);
        v2 += wB * bflo(qb0.y);  v3 += wB * bfhi(qb0.y);
    }
    if (m > 8) {
        const float wA = __shfl(wl, 8 + r, 64);
        const float wB = __shfl(wl, 12 + r, 64);
        v0 += wA * bflo(qa1.x);  v1 += wA * bfhi(qa1.x);
        v2 += wA * bflo(qa1.y);  v3 += wA * bfhi(qa1.y);
        v0 += wB * bflo(qb1.x);  v1 += wB * bfhi(qb1.x);
        v2 += wB * bflo(qb1.y);  v3 += wB * bfhi(qb1.y);
    }
    for (int j = 16; j < m; j += 8) {
        const int   jA = j + r;
        const int   jB = j + 4 + r;
        const int   dA = __shfl(dl, jA, 64);
        const float wA = __shfl(wl, jA, 64);
        const int   dB = __shfl(dl, jB, 64);
        const float wB = __shfl(wl, jB, 64);
        const uint2 qa = v_bf4[(size_t)dA * 16 + c];
        const uint2 qb = v_bf4[(size_t)dB * 16 + c];
        v0 += wA * bflo(qa.x);  v1 += wA * bfhi(qa.x);
        v2 += wA * bflo(qa.y);  v3 += wA * bfhi(qa.y);
        v0 += wB * bflo(qb.x);  v1 += wB * bfhi(qb.x);
        v2 += wB * bflo(qb.y);  v3 += wB * bfhi(qb.y);
    }

#pragma unroll
    for (int m2 = 1; m2 < 64; m2 <<= 1) {
        sumw  += __shfl_xor(sumw,  m2, 64);
        sumee += __shfl_xor(sumee, m2, 64);
    }
    v0 += __shfl_xor(v0, 16, 64);  v0 += __shfl_xor(v0, 32, 64);
    v1 += __shfl_xor(v1, 16, 64);  v1 += __shfl_xor(v1, 32, 64);
    v2 += __shfl_xor(v2, 16, 64);  v2 += __shfl_xor(v2, 32, 64);
    v3 += __shfl_xor(v3, 16, 64);  v3 += __shfl_xor(v3, 32, 64);

    const uint2 qu = u_bf4[(size_t)n * 16 + c];
    v0 += sumw * bflo(qu.x);
    v1 += sumw * bfhi(qu.x);
    v2 += sumw * bflo(qu.y);
    v3 += sumw * bfhi(qu.y);

    const float rden = (sumee == 0.f) ? 1e-12f : sumee;
    const float h0 = v0 / rden, h1 = v1 / rden, h2 = v2 / rden, h3 = v3 / rden;
    if (lane < 16) {
        float4 o;
        o.x = (h0 > 0.f) ? h0 : expm1f(h0);
        o.y = (h1 > 0.f) ? h1 : expm1f(h1);
        o.z = (h2 > 0.f) ? h2 : expm1f(h2);
        o.w = (h3 > 0.f) ? h3 : expm1f(h3);
        ((float4*)out)[(size_t)n * 16 + c] = o;
    }
}

// ---------------- probe kernels (scratch outputs, reps-amplified) ----------------

__global__ __launch_bounds__(256) void node_probe_kernel(
    const float* __restrict__ x, const float* __restrict__ a,
    const float* __restrict__ a2,
    unsigned short* __restrict__ u_bf, unsigned short* __restrict__ v_bf,
    float* __restrict__ su, float* __restrict__ sv,
    int* __restrict__ count, int N, int reps)
{
    __shared__ unsigned short xl[64 * PITCH];
    __shared__ unsigned short bl[128 * PITCH];
    const int t = threadIdx.x;
    const int rowbase = blockIdx.x * 64;

    for (int rep = 0; rep < reps; ++rep) {
        {
            const int row = t & 63, q = t >> 6;
            const int grow = rowbase + row;
            float xv[16];
            if (grow < N) {
                const float4* xp = (const float4*)(x + (size_t)grow * 64 + q * 16);
#pragma unroll
                for (int k = 0; k < 4; ++k) {
                    const float4 f = xp[k];
                    xv[k * 4 + 0] = f.x; xv[k * 4 + 1] = f.y;
                    xv[k * 4 + 2] = f.z; xv[k * 4 + 3] = f.w;
                }
            } else {
#pragma unroll
                for (int k = 0; k < 16; ++k) xv[k] = 0.f;
            }
            unsigned int uu[8];
#pragma unroll
            for (int k = 0; k < 8; ++k)
                uu[k] = (unsigned int)f2bf(xv[2 * k]) |
                        ((unsigned int)f2bf(xv[2 * k + 1]) << 16);
            uint4* dst = (uint4*)&xl[row * PITCH + q * 16];
            dst[0] = make_uint4(uu[0], uu[1], uu[2], uu[3]);
            dst[1] = make_uint4(uu[4], uu[5], uu[6], uu[7]);
        }
        {
            const int op = t >> 1, hh = (t & 1) * 32;
            const float* src = (op < 64) ? (a + op * 128 + hh)
                                         : (a + (op - 64) * 128 + 64 + hh);
            unsigned int uu[16];
#pragma unroll
            for (int k = 0; k < 16; ++k)
                uu[k] = (unsigned int)f2bf(src[2 * k]) |
                        ((unsigned int)f2bf(src[2 * k + 1]) << 16);
            uint4* dst = (uint4*)&bl[op * PITCH + hh];
#pragma unroll
            for (int k = 0; k < 4; ++k)
                dst[k] = make_uint4(uu[4 * k], uu[4 * k + 1], uu[4 * k + 2], uu[4 * k + 3]);
        }
        if (t < 64 && rowbase + t < N) count[rowbase + t] = 0;
        __syncthreads();

        const int w = t >> 6, l = t & 63;
        const int rw = w * 16;
        const int lr = l & 15, lk = l >> 4;

        const bf16x8 af0 = *(const bf16x8*)&xl[(rw + lr) * PITCH + lk * 8];
        const bf16x8 af1 = *(const bf16x8*)&xl[(rw + lr) * PITCH + 32 + lk * 8];

        float sup[4] = {0.f, 0.f, 0.f, 0.f}, svp[4] = {0.f, 0.f, 0.f, 0.f};

        for (int ct = 0; ct < 8; ++ct) {
            const bf16x8 bf0 = *(const bf16x8*)&bl[(ct * 16 + lr) * PITCH + lk * 8];
            const bf16x8 bf1 = *(const bf16x8*)&bl[(ct * 16 + lr) * PITCH + 32 + lk * 8];
            f32x4 acc = {0.f, 0.f, 0.f, 0.f};
            acc = __builtin_amdgcn_mfma_f32_16x16x32_bf16(af0, bf0, acc, 0, 0, 0);
            acc = __builtin_amdgcn_mfma_f32_16x16x32_bf16(af1, bf1, acc, 0, 0, 0);

            const int col = ct * 16 + lr;
            unsigned short* dst = (ct < 4) ? u_bf : v_bf;
            const int o = (ct < 4) ? col : col - 64;
            const float a2o = a2[o];
#pragma unroll
            for (int r = 0; r < 4; ++r) {
                const int grow = rowbase + rw + lk * 4 + r;
                if (grow < N) dst[(size_t)grow * 64 + o] = f2bf(acc[r]);
                if (ct < 4) sup[r] += acc[r] * a2o; else svp[r] += acc[r] * a2o;
            }
        }

#pragma unroll
        for (int r = 0; r < 4; ++r) {
#pragma unroll
            for (int m = 1; m < 16; m <<= 1) {
                sup[r] += __shfl_xor(sup[r], m, 64);
                svp[r] += __shfl_xor(svp[r], m, 64);
            }
        }
        if (lr == 0) {
#pragma unroll
            for (int r = 0; r < 4; ++r) {
                const int grow = rowbase + rw + lk * 4 + r;
                if (grow < N) { su[grow] = sup[r]; sv[grow] = svp[r]; }
            }
        }
        __syncthreads();
        asm volatile("" ::: "memory");
    }
}

// probe variant: slot & 63 -> every rep does atomic RMW + unconditional scatter
__global__ __launch_bounds__(256) void histplace_probe_kernel(
    const int* __restrict__ edge, const int* __restrict__ etype,
    int* __restrict__ count, unsigned int* __restrict__ csr,
    int E, int N, int R, int reps)
{
    const int i4 = (blockIdx.x * 256 + threadIdx.x) * 4;
    for (int rep = 0; rep < reps; ++rep) {
        if (i4 + 3 < E) {
            const int4 s4 = *(const int4*)(edge + i4);
            const int4 d4 = *(const int4*)(edge + (size_t)E + i4);
            const int4 t4 = *(const int4*)(etype + i4);
            const int ss[4] = {s4.x, s4.y, s4.z, s4.w};
            const int dd[4] = {d4.x, d4.y, d4.z, d4.w};
            const int tt[4] = {t4.x, t4.y, t4.z, t4.w};
#pragma unroll
            for (int k = 0; k < 4; ++k) {
                if ((unsigned)ss[k] < (unsigned)N && (unsigned)dd[k] < (unsigned)N &&
                    (unsigned)tt[k] < (unsigned)R) {
                    const int slot = atomicAdd(&count[ss[k]], 1) & 63;
                    csr[(size_t)ss[k] * SLOTS + slot] =
                        ((unsigned)dd[k] << 8) | (unsigned)tt[k];
                }
            }
        }
        asm volatile("" ::: "memory");
    }
}

__global__ __launch_bounds__(256) void aggregate_probe_kernel(
    const int* __restrict__ count,
    const unsigned int* __restrict__ csr,
    const uint2* __restrict__ u_bf4,
    const uint2* __restrict__ v_bf4,
    const float* __restrict__ su, const float* __restrict__ sv,
    const float* __restrict__ G, int R,
    float* __restrict__ out, int N, int reps)
{
    const int wave = threadIdx.x >> 6;
    const int lane = threadIdx.x & 63;
    const int n = blockIdx.x * 4 + wave;
    const int c = lane & 15;
    const int r = lane >> 4;

    for (int rep = 0; rep < reps; ++rep) {
        if (n < N) {
            const int m = min(count[n], SLOTS);
            const unsigned int* __restrict__ row = csr + (size_t)n * SLOTS;
            const float su_n = su[n];
            const float* __restrict__ Gn = G + (size_t)n * R;

            float v0 = 0.f, v1 = 0.f, v2 = 0.f, v3 = 0.f;

            unsigned pe = 0;
            if (lane < m) pe = row[lane];
            const int dl = (int)(pe >> 8);

            const int   dA0 = __shfl(dl, 0 + r, 64);
            const int   dB0 = __shfl(dl, 4 + r, 64);
            const uint2 qa0 = v_bf4[(size_t)dA0 * 16 + c];
            const uint2 qb0 = v_bf4[(size_t)dB0 * 16 + c];
            uint2 qa1 = make_uint2(0u, 0u), qb1 = make_uint2(0u, 0u);
            if (m > 8) {
                const int dA1 = __shfl(dl, 8 + r, 64);
                const int dB1 = __shfl(dl, 12 + r, 64);
                qa1 = v_bf4[(size_t)dA1 * 16 + c];
                qb1 = v_bf4[(size_t)dB1 * 16 + c];
            }

            float wl = 0.f, eel = 0.f;
            if (lane < m) {
                const int t = (int)(pe & 255u);
                const float g   = 0.5f * (Gn[t] + G[(size_t)dl * R + t]);
                const float raw = g * (su_n + sv[dl]);
                const float lr  = raw > 0.f ? raw : LRELU_ALPHA * raw;
                const float ee  = __expf(-lr);
                eel = ee;
                wl  = ee * g;
            }
            float sumw = wl, sumee = eel;

            {
                const float wA = __shfl(wl, 0 + r, 64);
                const float wB = __shfl(wl, 4 + r, 64);
                v0 += wA * bflo(qa0.x);  v1 += wA * bfhi(qa0.x);
                v2 += wA * bflo(qa0.y);  v3 += wA * bfhi(qa0.y);
                v0 += wB * bflo(qb0.x);  v1 += wB * bfhi(qb0.x);
                v2 += wB * bflo(qb0.y);  v3 += wB * bfhi(qb0.y);
            }
            if (m > 8) {
                const float wA = __shfl(wl, 8 + r, 64);
                const float wB = __shfl(wl, 12 + r, 64);
                v0 += wA * bflo(qa1.x);  v1 += wA * bfhi(qa1.x);
                v2 += wA * bflo(qa1.y);  v3 += wA * bfhi(qa1.y);
                v0 += wB * bflo(qb1.x);  v1 += wB * bfhi(qb1.x);
                v2 += wB * bflo(qb1.y);  v3 += wB * bfhi(qb1.y);
            }
            for (int j = 16; j < m; j += 8) {
                const int   jA = j + r;
                const int   jB = j + 4 + r;
                const int   dA = __shfl(dl, jA, 64);
                const float wA = __shfl(wl, jA, 64);
                const int   dB = __shfl(dl, jB, 64);
                const float wB = __shfl(wl, jB, 64);
                const uint2 qa = v_bf4[(size_t)dA * 16 + c];
                const uint2 qb = v_bf4[(size_t)dB * 16 + c];
                v0 += wA * bflo(qa.x);  v1 += wA * bfhi(qa.x);
                v2 += wA * bflo(qa.y);  v3 += wA * bfhi(qa.y);
                v0 += wB * bflo(qb.x);  v1 += wB * bfhi(qb.x);
                v2 += wB * bflo(qb.y);  v3 += wB * bfhi(qb.y);
            }

#pragma unroll
            for (int m2 = 1; m2 < 64; m2 <<= 1) {
                sumw  += __shfl_xor(sumw,  m2, 64);
                sumee += __shfl_xor(sumee, m2, 64);
            }
            v0 += __shfl_xor(v0, 16, 64);  v0 += __shfl_xor(v0, 32, 64);
            v1 += __shfl_xor(v1, 16, 64);  v1 += __shfl_xor(v1, 32, 64);
            v2 += __shfl_xor(v2, 16, 64);  v2 += __shfl_xor(v2, 32, 64);
            v3 += __shfl_xor(v3, 16, 64);  v3 += __shfl_xor(v3, 32, 64);

            const uint2 qu = u_bf4[(size_t)n * 16 + c];
            v0 += sumw * bflo(qu.x);
            v1 += sumw * bfhi(qu.x);
            v2 += sumw * bflo(qu.y);
            v3 += sumw * bfhi(qu.y);

            const float rden = (sumee == 0.f) ? 1e-12f : sumee;
            const float h0 = v0 / rden, h1 = v1 / rden, h2 = v2 / rden, h3 = v3 / rden;
            if (lane < 16) {
                float4 o;
                o.x = (h0 > 0.f) ? h0 : expm1f(h0);
                o.y = (h1 > 0.f) ? h1 : expm1f(h1);
                o.z = (h2 > 0.f) ? h2 : expm1f(h2);
                o.w = (h3 > 0.f) ? h3 : expm1f(h3);
                ((float4*)out)[(size_t)n * 16 + c] = o;
            }
        }
        asm volatile("" ::: "memory");
    }
}

extern "C" void kernel_launch(void* const* d_in, const int* in_sizes, int n_in,
                              void* d_out, int out_size, void* d_ws, size_t ws_size,
                              hipStream_t stream)
{
    const float* x     = (const float*)d_in[0];
    const int*   edge  = (const int*)d_in[1];
    const int*   etype = (const int*)d_in[3];
    const float* G     = (const float*)d_in[4];
    const float* a     = (const float*)d_in[5];
    const float* a2    = (const float*)d_in[6];

    const int N = in_sizes[0] / 64;
    const int E = in_sizes[1] / 2;
    const int R = in_sizes[4] / N;

    float* out = (float*)d_out;

    // real workspace (~26.2 MB)
    unsigned short* u_bf = (unsigned short*)d_ws;
    unsigned short* v_bf = u_bf + (size_t)N * 64;
    float* su     = (float*)(v_bf + (size_t)N * 64);
    float* sv     = su + N;
    int*   count  = (int*)(sv + N);
    unsigned int* csr = (unsigned int*)(count + N);
    char* scratch = (char*)(csr + (size_t)N * SLOTS);
    scratch = (char*)((((uintptr_t)scratch) + 255) & ~(uintptr_t)255);

    const size_t real_bytes   = (size_t)(scratch - (char*)d_ws);
    const size_t scratch_need = (size_t)14 * 1024 * 1024;
    const bool   probes_ok    = ws_size >= real_bytes + scratch_need;

    // ---- real pipeline (identical to R15) ----
    node_mfma_kernel<<<dim3((N + 63) / 64), dim3(256), 0, stream>>>(
        x, a, a2, u_bf, v_bf, su, sv, count, N);
    histplace_kernel<<<dim3(((E + 3) / 4 + 255) / 256), dim3(256), 0, stream>>>(
        edge, etype, count, csr, E, N, R);
    aggregate_kernel<<<dim3((N + 3) / 4), dim3(256), 0, stream>>>(
        count, csr, (const uint2*)u_bf, (const uint2*)v_bf,
        su, sv, G, R, out, N);

    // ---- probes (scratch; read only finalized real data) ----
    if (probes_ok) {
        // node probe overlay: u(6.4M) v(6.4M) su/sv/count (0.6M)
        unsigned short* s_u  = (unsigned short*)scratch;
        unsigned short* s_v  = s_u + (size_t)N * 64;
        float* s_su  = (float*)(s_v + (size_t)N * 64);
        float* s_sv  = s_su + N;
        int*   s_cnt = (int*)(s_sv + N);
        // histplace probe overlay: count (0.2M) + csr (12.8M)
        int*   s_cnt2 = (int*)scratch;
        unsigned int* s_csr = (unsigned int*)(s_cnt2 + N);
        // aggregate probe overlay: out (12.8M)
        float* s_out = (float*)scratch;

        node_probe_kernel<<<dim3((N + 63) / 64), dim3(256), 0, stream>>>(
            x, a, a2, s_u, s_v, s_su, s_sv, s_cnt, N, REPS_NODE);
        histplace_probe_kernel<<<dim3(((E + 3) / 4 + 255) / 256), dim3(256), 0, stream>>>(
            edge, etype, s_cnt2, s_csr, E, N, R, REPS_HP);
        aggregate_probe_kernel<<<dim3((N + 3) / 4), dim3(256), 0, stream>>>(
            count, csr, (const uint2*)u_bf, (const uint2*)v_bf,
            su, sv, G, R, s_out, N, REPS_AGG);
    }
}

// Round 17
// 103.444 us; speedup vs baseline: 17.6528x; 17.6528x over previous
//
#include <hip/hip_runtime.h>
#include <hip/hip_bf16.h>

// GrCNet attention layer — 3-kernel pipeline with fixed-slot edge bins.
//   u[n] = W1 x[n], v[n] = W2 x[n]   (a = [W1 | W2], [64,128] row-major)
//   su[n] = u[n].a2, sv[n] = v[n].a2  (from f32 MFMA accumulator)
//   edge e: g = 0.5*(G[s,t]+G[d,t]); ee = exp(-lrelu(g*(su[s]+sv[d]))); w = ee*g
//   bins: csr[s*64 + slot] = (d<<8)|t, slot = atomicAdd(count[s])
//   h[n] = elu( ((Σw)·u[n] + Σ w·v[d]) / Σee )
//
// Round 17: R16 probe showed histplace = ~60us (55% of pipeline!) at 34%
// occupancy, VALUBusy 0.4% — latency-bound with a grid (782 blocks) too small
// to hide the atomic->scatter chain. Fix: 1 edge/thread (3125 blocks, 12.5k
// waves -> full residency, 4x latency hiding). Everything else unchanged.

#define LRELU_ALPHA 0.2f
#define PITCH 72   // bf16 elems per LDS row: 64 + 8 pad
#define SLOTS 64

typedef __attribute__((ext_vector_type(8))) short bf16x8;
typedef __attribute__((ext_vector_type(4))) float f32x4;

__device__ __forceinline__ float bflo(unsigned int q) {
    return __int_as_float((int)(q << 16));
}
__device__ __forceinline__ float bfhi(unsigned int q) {
    return __int_as_float((int)(q & 0xffff0000u));
}
__device__ __forceinline__ unsigned short f2bf(float f) {
    __hip_bfloat16 h = __float2bfloat16(f);
    return *reinterpret_cast<unsigned short*>(&h);
}

// MFMA node transform (B-prep fused): block = 64 rows, 4 waves x 8 col-tiles.
// C layout (m89): col = lane&15, row = (lane>>4)*4 + reg.
__global__ __launch_bounds__(256) void node_mfma_kernel(
    const float* __restrict__ x, const float* __restrict__ a,
    const float* __restrict__ a2,
    unsigned short* __restrict__ u_bf, unsigned short* __restrict__ v_bf,
    float* __restrict__ su, float* __restrict__ sv,
    int* __restrict__ count, int N)
{
    __shared__ unsigned short xl[64 * PITCH];
    __shared__ unsigned short bl[128 * PITCH];
    const int t = threadIdx.x;
    const int rowbase = blockIdx.x * 64;

    {
        const int row = t & 63, q = t >> 6;
        const int grow = rowbase + row;
        float xv[16];
        if (grow < N) {
            const float4* xp = (const float4*)(x + (size_t)grow * 64 + q * 16);
#pragma unroll
            for (int k = 0; k < 4; ++k) {
                const float4 f = xp[k];
                xv[k * 4 + 0] = f.x; xv[k * 4 + 1] = f.y;
                xv[k * 4 + 2] = f.z; xv[k * 4 + 3] = f.w;
            }
        } else {
#pragma unroll
            for (int k = 0; k < 16; ++k) xv[k] = 0.f;
        }
        unsigned int uu[8];
#pragma unroll
        for (int k = 0; k < 8; ++k)
            uu[k] = (unsigned int)f2bf(xv[2 * k]) |
                    ((unsigned int)f2bf(xv[2 * k + 1]) << 16);
        uint4* dst = (uint4*)&xl[row * PITCH + q * 16];
        dst[0] = make_uint4(uu[0], uu[1], uu[2], uu[3]);
        dst[1] = make_uint4(uu[4], uu[5], uu[6], uu[7]);
    }
    {
        const int op = t >> 1, hh = (t & 1) * 32;
        const float* src = (op < 64) ? (a + op * 128 + hh)
                                     : (a + (op - 64) * 128 + 64 + hh);
        unsigned int uu[16];
#pragma unroll
        for (int k = 0; k < 16; ++k)
            uu[k] = (unsigned int)f2bf(src[2 * k]) |
                    ((unsigned int)f2bf(src[2 * k + 1]) << 16);
        uint4* dst = (uint4*)&bl[op * PITCH + hh];
#pragma unroll
        for (int k = 0; k < 4; ++k)
            dst[k] = make_uint4(uu[4 * k], uu[4 * k + 1], uu[4 * k + 2], uu[4 * k + 3]);
    }
    if (t < 64 && rowbase + t < N) count[rowbase + t] = 0;
    __syncthreads();

    const int w = t >> 6, l = t & 63;
    const int rw = w * 16;
    const int lr = l & 15, lk = l >> 4;

    const bf16x8 af0 = *(const bf16x8*)&xl[(rw + lr) * PITCH + lk * 8];
    const bf16x8 af1 = *(const bf16x8*)&xl[(rw + lr) * PITCH + 32 + lk * 8];

    float sup[4] = {0.f, 0.f, 0.f, 0.f}, svp[4] = {0.f, 0.f, 0.f, 0.f};

    for (int ct = 0; ct < 8; ++ct) {
        const bf16x8 bf0 = *(const bf16x8*)&bl[(ct * 16 + lr) * PITCH + lk * 8];
        const bf16x8 bf1 = *(const bf16x8*)&bl[(ct * 16 + lr) * PITCH + 32 + lk * 8];
        f32x4 acc = {0.f, 0.f, 0.f, 0.f};
        acc = __builtin_amdgcn_mfma_f32_16x16x32_bf16(af0, bf0, acc, 0, 0, 0);
        acc = __builtin_amdgcn_mfma_f32_16x16x32_bf16(af1, bf1, acc, 0, 0, 0);

        const int col = ct * 16 + lr;
        unsigned short* dst = (ct < 4) ? u_bf : v_bf;
        const int o = (ct < 4) ? col : col - 64;
        const float a2o = a2[o];
#pragma unroll
        for (int r = 0; r < 4; ++r) {
            const int grow = rowbase + rw + lk * 4 + r;
            if (grow < N) dst[(size_t)grow * 64 + o] = f2bf(acc[r]);
            if (ct < 4) sup[r] += acc[r] * a2o; else svp[r] += acc[r] * a2o;
        }
    }

#pragma unroll
    for (int r = 0; r < 4; ++r) {
#pragma unroll
        for (int m = 1; m < 16; m <<= 1) {
            sup[r] += __shfl_xor(sup[r], m, 64);
            svp[r] += __shfl_xor(svp[r], m, 64);
        }
    }
    if (lr == 0) {
#pragma unroll
        for (int r = 0; r < 4; ++r) {
            const int grow = rowbase + rw + lk * 4 + r;
            if (grow < N) { su[grow] = sup[r]; sv[grow] = svp[r]; }
        }
    }
}

// fused histogram + placement, ONE edge per thread: full-residency grid so
// the atomic->scatter dependency chain is hidden by TLP.
__global__ __launch_bounds__(256) void histplace_kernel(
    const int* __restrict__ edge, const int* __restrict__ etype,
    int* __restrict__ count, unsigned int* __restrict__ csr,
    int E, int N, int R)
{
    const int i = blockIdx.x * 256 + threadIdx.x;
    if (i >= E) return;
    const int s = edge[i];
    const int d = edge[(size_t)E + i];
    const int t = etype[i];
    if ((unsigned)s >= (unsigned)N || (unsigned)d >= (unsigned)N ||
        (unsigned)t >= (unsigned)R) return;

    const int slot = atomicAdd(&count[s], 1);
    if (slot < SLOTS)
        csr[(size_t)s * SLOTS + slot] = ((unsigned)d << 8) | (unsigned)t;
}

// one WAVE per node, single chunk (m = count[n] <= 64).
// lane = (r:2)(c:4): channel quad c, entry slot r. v-prefetch j=0/8 overlaps score.
__global__ __launch_bounds__(256) void aggregate_kernel(
    const int* __restrict__ count,
    const unsigned int* __restrict__ csr,
    const uint2* __restrict__ u_bf4,
    const uint2* __restrict__ v_bf4,
    const float* __restrict__ su, const float* __restrict__ sv,
    const float* __restrict__ G, int R,
    float* __restrict__ out, int N)
{
    const int wave = threadIdx.x >> 6;
    const int lane = threadIdx.x & 63;
    const int n = blockIdx.x * 4 + wave;
    if (n >= N) return;

    const int m = min(count[n], SLOTS);
    const unsigned int* __restrict__ row = csr + (size_t)n * SLOTS;

    const int c = lane & 15;
    const int r = lane >> 4;

    const float su_n = su[n];
    const float* __restrict__ Gn = G + (size_t)n * R;

    float v0 = 0.f, v1 = 0.f, v2 = 0.f, v3 = 0.f;

    unsigned pe = 0;
    if (lane < m) pe = row[lane];
    const int dl = (int)(pe >> 8);

    const int   dA0 = __shfl(dl, 0 + r, 64);
    const int   dB0 = __shfl(dl, 4 + r, 64);
    const uint2 qa0 = v_bf4[(size_t)dA0 * 16 + c];
    const uint2 qb0 = v_bf4[(size_t)dB0 * 16 + c];
    uint2 qa1 = make_uint2(0u, 0u), qb1 = make_uint2(0u, 0u);
    if (m > 8) {
        const int dA1 = __shfl(dl, 8 + r, 64);
        const int dB1 = __shfl(dl, 12 + r, 64);
        qa1 = v_bf4[(size_t)dA1 * 16 + c];
        qb1 = v_bf4[(size_t)dB1 * 16 + c];
    }

    float wl = 0.f, eel = 0.f;
    if (lane < m) {
        const int t = (int)(pe & 255u);
        const float g   = 0.5f * (Gn[t] + G[(size_t)dl * R + t]);
        const float raw = g * (su_n + sv[dl]);
        const float lr  = raw > 0.f ? raw : LRELU_ALPHA * raw;
        const float ee  = __expf(-lr);
        eel = ee;
        wl  = ee * g;
    }
    float sumw = wl, sumee = eel;

    {
        const float wA = __shfl(wl, 0 + r, 64);
        const float wB = __shfl(wl, 4 + r, 64);
        v0 += wA * bflo(qa0.x);  v1 += wA * bfhi(qa0.x);
        v2 += wA * bflo(qa0.y);  v3 += wA * bfhi(qa0.y);
        v0 += wB * bflo(qb0.x);  v1 += wB * bfhi(qb0.x);
        v2 += wB * bflo(qb0.y);  v3 += wB * bfhi(qb0.y);
    }
    if (m > 8) {
        const float wA = __shfl(wl, 8 + r, 64);
        const float wB = __shfl(wl, 12 + r, 64);
        v0 += wA * bflo(qa1.x);  v1 += wA * bfhi(qa1.x);
        v2 += wA * bflo(qa1.y);  v3 += wA * bfhi(qa1.y);
        v0 += wB * bflo(qb1.x);  v1 += wB * bfhi(qb1.x);
        v2 += wB * bflo(qb1.y);  v3 += wB * bfhi(qb1.y);
    }
    for (int j = 16; j < m; j += 8) {
        const int   jA = j + r;
        const int   jB = j + 4 + r;
        const int   dA = __shfl(dl, jA, 64);
        const float wA = __shfl(wl, jA, 64);
        const int   dB = __shfl(dl, jB, 64);
        const float wB = __shfl(wl, jB, 64);
        const uint2 qa = v_bf4[(size_t)dA * 16 + c];
        const uint2 qb = v_bf4[(size_t)dB * 16 + c];
        v0 += wA * bflo(qa.x);  v1 += wA * bfhi(qa.x);
        v2 += wA * bflo(qa.y);  v3 += wA * bfhi(qa.y);
        v0 += wB * bflo(qb.x);  v1 += wB * bfhi(qb.x);
        v2 += wB * bflo(qb.y);  v3 += wB * bfhi(qb.y);
    }

#pragma unroll
    for (int m2 = 1; m2 < 64; m2 <<= 1) {
        sumw  += __shfl_xor(sumw,  m2, 64);
        sumee += __shfl_xor(sumee, m2, 64);
    }
    v0 += __shfl_xor(v0, 16, 64);  v0 += __shfl_xor(v0, 32, 64);
    v1 += __shfl_xor(v1, 16, 64);  v1 += __shfl_xor(v1, 32, 64);
    v2 += __shfl_xor(v2, 16, 64);  v2 += __shfl_xor(v2, 32, 64);
    v3 += __shfl_xor(v3, 16, 64);  v3 += __shfl_xor(v3, 32, 64);

    const uint2 qu = u_bf4[(size_t)n * 16 + c];
    v0 += sumw * bflo(qu.x);
    v1 += sumw * bfhi(qu.x);
    v2 += sumw * bflo(qu.y);
    v3 += sumw * bfhi(qu.y);

    const float rden = (sumee == 0.f) ? 1e-12f : sumee;
    const float h0 = v0 / rden, h1 = v1 / rden, h2 = v2 / rden, h3 = v3 / rden;
    if (lane < 16) {
        float4 o;
        o.x = (h0 > 0.f) ? h0 : expm1f(h0);
        o.y = (h1 > 0.f) ? h1 : expm1f(h1);
        o.z = (h2 > 0.f) ? h2 : expm1f(h2);
        o.w = (h3 > 0.f) ? h3 : expm1f(h3);
        ((float4*)out)[(size_t)n * 16 + c] = o;
    }
}

extern "C" void kernel_launch(void* const* d_in, const int* in_sizes, int n_in,
                              void* d_out, int out_size, void* d_ws, size_t ws_size,
                              hipStream_t stream)
{
    const float* x     = (const float*)d_in[0];
    const int*   edge  = (const int*)d_in[1];
    // d_in[2] = edge_embed: unused by the reference computation
    const int*   etype = (const int*)d_in[3];
    const float* G     = (const float*)d_in[4];
    const float* a     = (const float*)d_in[5];
    const float* a2    = (const float*)d_in[6];

    const int N = in_sizes[0] / 64;   // 50000
    const int E = in_sizes[1] / 2;    // 800000
    const int R = in_sizes[4] / N;    // 200

    float* out = (float*)d_out;

    // workspace (~26.2 MB): u_bf | v_bf (bf16) | su | sv | count | csr[N*64]
    unsigned short* u_bf = (unsigned short*)d_ws;
    unsigned short* v_bf = u_bf + (size_t)N * 64;
    float* su     = (float*)(v_bf + (size_t)N * 64);
    float* sv     = su + N;
    int*   count  = (int*)(sv + N);
    unsigned int* csr = (unsigned int*)(count + N);

    node_mfma_kernel<<<dim3((N + 63) / 64), dim3(256), 0, stream>>>(
        x, a, a2, u_bf, v_bf, su, sv, count, N);
    histplace_kernel<<<dim3((E + 255) / 256), dim3(256), 0, stream>>>(
        edge, etype, count, csr, E, N, R);
    aggregate_kernel<<<dim3((N + 3) / 4), dim3(256), 0, stream>>>(
        count, csr, (const uint2*)u_bf, (const uint2*)v_bf,
        su, sv, G, R, out, N);
}